// Round 7
// baseline (39.917 us; speedup 1.0000x reference)
//
#include <hip/hip_runtime.h>

typedef float    f32x4  __attribute__((ext_vector_type(4)));
typedef float    f32x16 __attribute__((ext_vector_type(16)));
typedef _Float16 half8  __attribute__((ext_vector_type(8)));

constexpr int NB = 8;
constexpr int NQ = 2048;
constexpr int NKEY = 2048;
constexpr int DD = 64;
constexpr int KB = 64;   // keys per wave-iteration (two 32-key chunks)

// scores kept in log2 domain: fold log2(e) into the 1/sqrt(d) scale
#define QSCALE (0.125f * 1.44269504088896340736f)

__device__ inline unsigned pkh(float a, float b) {
    return __builtin_bit_cast(unsigned, __builtin_amdgcn_cvt_pkrtz(a, b));
}

// P (f32 C-layout regs) -> f16 A-fragments, then PV from global V.
// Verified R5/R6: A0 = keys hi*8+{0..7}, A1 = keys 16+hi*8+{0..7};
// vb for (t,dblk): V[kb + t*16 + hi*8 + j][dblk*32 + ql].
__device__ __forceinline__ void pv_chunk(
    const f32x16& sv, const float* __restrict__ vbase /* row kb, col 0 */,
    int hi, int ql, f32x16& o0, f32x16& o1)
{
    const unsigned w0 = pkh(sv[0],  sv[1]),  w1 = pkh(sv[2],  sv[3]);
    const unsigned w2 = pkh(sv[4],  sv[5]),  w3 = pkh(sv[6],  sv[7]);
    const unsigned w4 = pkh(sv[8],  sv[9]),  w5 = pkh(sv[10], sv[11]);
    const unsigned w6 = pkh(sv[12], sv[13]), w7 = pkh(sv[14], sv[15]);
    const unsigned p0 = __shfl_xor(w0, 32), p1 = __shfl_xor(w1, 32);
    const unsigned p2 = __shfl_xor(w2, 32), p3 = __shfl_xor(w3, 32);
    const unsigned p4 = __shfl_xor(w4, 32), p5 = __shfl_xor(w5, 32);
    const unsigned p6 = __shfl_xor(w6, 32), p7 = __shfl_xor(w7, 32);
    const bool h1 = (hi != 0);
    union { unsigned u[4]; half8 h; } A0, A1;
    A0.u[0] = h1 ? p2 : w0;  A0.u[1] = h1 ? p3 : w1;
    A0.u[2] = h1 ? w2 : p0;  A0.u[3] = h1 ? w3 : p1;
    A1.u[0] = h1 ? p6 : w4;  A1.u[1] = h1 ? p7 : w5;
    A1.u[2] = h1 ? w6 : p4;  A1.u[3] = h1 ? w7 : p5;

#pragma unroll
    for (int t = 0; t < 2; ++t) {
        const float* vr = vbase + (size_t)(t * 16 + hi * 8) * DD + ql;
        half8 vb0, vb1;
#pragma unroll
        for (int j = 0; j < 8; ++j) {
            vb0[j] = (_Float16)vr[(size_t)j * DD];
            vb1[j] = (_Float16)vr[(size_t)j * DD + 32];
        }
        const half8 pa = (t == 0) ? A0.h : A1.h;
        o0 = __builtin_amdgcn_mfma_f32_32x32x16_f16(pa, vb0, o0, 0, 0, 0);
        o1 = __builtin_amdgcn_mfma_f32_32x32x16_f16(pa, vb1, o1, 0, 0, 0);
    }
}

// Fused flash attention: 1 block = 4 waves x same 32-q-row tile,
// split-K across waves, LDS merge at the end. No barriers in main loop.
__global__ __launch_bounds__(256) void attn_fused(
    const float* __restrict__ Qp, const float* __restrict__ Kp,
    const float* __restrict__ Vp, const int* __restrict__ VL,
    float* __restrict__ Op)
{
    __shared__ float Obuf[4][32][64];            // 32 KB wave-partial O
    __shared__ float Mb[4][32], Lb[4][32], Tb[32];

    const int tid  = threadIdx.x;
    const int wv   = tid >> 6;
    const int lane = tid & 63;
    const int ql   = lane & 31;
    const int hi   = lane >> 5;

    const int b  = blockIdx.x >> 6;              // 64 q-tiles per batch
    const int qt = blockIdx.x & 63;
    const int qbase = qt * 32;

    const int vlen = VL[b];
    const int numt = (vlen + KB - 1) / KB;

    // ---- Q B-fragments: lane holds Q[qbase+ql][d = c*16 + hi*8 + j] ----
    const float* qsrc = Qp + ((size_t)b * NQ + qbase + ql) * DD;
    half8 qf[4];
#pragma unroll
    for (int c = 0; c < 4; ++c) {
        f32x4 f0 = *(const f32x4*)(qsrc + c * 16 + hi * 8);
        f32x4 f1 = *(const f32x4*)(qsrc + c * 16 + hi * 8 + 4);
        half8 h;
#pragma unroll
        for (int j = 0; j < 4; ++j) {
            h[j]     = (_Float16)(f0[j] * QSCALE);
            h[4 + j] = (_Float16)(f1[j] * QSCALE);
        }
        qf[c] = h;
    }

    f32x16 o0 = {}, o1 = {};
    float mrun = -1e30f, lrun = 0.f;

    // ---- main loop: wave wv owns key tiles wv, wv+4, ... (no barriers) ----
    for (int t = wv; t < numt; t += 4) {
        const int kbase = t * KB;

        // K fragments straight from global (L2-resident), rows ql / ql+32
        const float* ka = Kp + ((size_t)b * NKEY + kbase + ql) * DD;
        f32x16 svA = {}, svB = {};
#pragma unroll
        for (int c = 0; c < 4; ++c) {
            const int col = c * 16 + hi * 8;
            f32x4 a0 = *(const f32x4*)(ka + col);
            f32x4 a1 = *(const f32x4*)(ka + col + 4);
            f32x4 b0 = *(const f32x4*)(ka + (size_t)32 * DD + col);
            f32x4 b1 = *(const f32x4*)(ka + (size_t)32 * DD + col + 4);
            half8 kfA, kfB;
#pragma unroll
            for (int j = 0; j < 4; ++j) {
                kfA[j] = (_Float16)a0[j];  kfA[4 + j] = (_Float16)a1[j];
                kfB[j] = (_Float16)b0[j];  kfB[4 + j] = (_Float16)b1[j];
            }
            svA = __builtin_amdgcn_mfma_f32_32x32x16_f16(kfA, qf[c], svA, 0, 0, 0);
            svB = __builtin_amdgcn_mfma_f32_32x32x16_f16(kfB, qf[c], svB, 0, 0, 0);
        }

        // ---- mask (boundary tile only; wave-uniform branch) ----
        if (kbase + KB > vlen) {
#pragma unroll
            for (int r = 0; r < 16; ++r) {
                const int krow = (r & 3) + 8 * (r >> 2) + 4 * hi;
                svA[r] = (kbase + krow < vlen)      ? svA[r] : -1e30f;
                svB[r] = (kbase + 32 + krow < vlen) ? svB[r] : -1e30f;
            }
        }

        // ---- online softmax in log2 domain (lane state is q = ql) ----
        float mx[16];
#pragma unroll
        for (int r = 0; r < 16; ++r) mx[r] = fmaxf(svA[r], svB[r]);
#pragma unroll
        for (int st = 8; st > 0; st >>= 1)
#pragma unroll
            for (int r = 0; r < st; ++r) mx[r] = fmaxf(mx[r], mx[r + st]);
        float mr = fmaxf(mx[0], __shfl_xor(mx[0], 32));

        // defer-max: skip rescale if max grew <= 8 (P bounded by 2^8)
        if (!__all(mr <= mrun + 8.f)) {
            const float mn = fmaxf(mrun, mr);
            const float alpha = __builtin_amdgcn_exp2f(mrun - mn);
            lrun *= alpha;
            mrun = mn;
#pragma unroll
            for (int r = 0; r < 16; ++r) {
                const int qr = (r & 3) + 8 * (r >> 2) + 4 * hi;
                const float ar = __shfl(alpha, qr);
                o0[r] *= ar;
                o1[r] *= ar;
            }
        }

#pragma unroll
        for (int r = 0; r < 16; ++r) {
            svA[r] = __builtin_amdgcn_exp2f(svA[r] - mrun);
            svB[r] = __builtin_amdgcn_exp2f(svB[r] - mrun);
        }
        float sx[16];
#pragma unroll
        for (int r = 0; r < 16; ++r) sx[r] = svA[r] + svB[r];
#pragma unroll
        for (int st = 8; st > 0; st >>= 1)
#pragma unroll
            for (int r = 0; r < st; ++r) sx[r] += sx[r + st];
        lrun += sx[0] + __shfl_xor(sx[0], 32);

        // ---- PV for both chunks (V direct from global, L2-resident) ----
        const float* vbase = Vp + ((size_t)b * NKEY + kbase) * DD;
        pv_chunk(svA, vbase, hi, ql, o0, o1);
        pv_chunk(svB, vbase + (size_t)32 * DD, hi, ql, o0, o1);
    }

    // ---- cross-wave merge via LDS ----
    if (hi == 0) { Mb[wv][ql] = mrun; Lb[wv][ql] = lrun; }
    __syncthreads();

    // per-lane combine for q = ql
    float Mtot = -1e30f;
#pragma unroll
    for (int w = 0; w < 4; ++w)
        if (Lb[w][ql] > 0.f) Mtot = fmaxf(Mtot, Mb[w][ql]);
    float Ltot = 0.f;
#pragma unroll
    for (int w = 0; w < 4; ++w) {
        const float lw = Lb[w][ql];
        if (lw > 0.f) Ltot += lw * __builtin_amdgcn_exp2f(Mb[w][ql] - Mtot);
    }
    const float wown = (lrun > 0.f) ? __builtin_amdgcn_exp2f(mrun - Mtot) : 0.f;
    if (wv == 0 && hi == 0) Tb[ql] = Ltot;

    // scale own O by per-row weight, write to LDS
#pragma unroll
    for (int r = 0; r < 16; ++r) {
        const int qr = (r & 3) + 8 * (r >> 2) + 4 * hi;
        const float wr = __shfl(wown, qr);
        Obuf[wv][qr][ql]      = o0[r] * wr;
        Obuf[wv][qr][ql + 32] = o1[r] * wr;
    }
    __syncthreads();

    // readback: wave wv handles q rows wv*8 .. wv*8+7; lane = d
#pragma unroll
    for (int k = 0; k < 8; ++k) {
        const int q = wv * 8 + k;
        const float sum = Obuf[0][q][lane] + Obuf[1][q][lane]
                        + Obuf[2][q][lane] + Obuf[3][q][lane];
        Op[((size_t)b * NQ + qbase + q) * DD + lane] = sum / Tb[q];
    }
}

extern "C" void kernel_launch(void* const* d_in, const int* in_sizes, int n_in,
                              void* d_out, int out_size, void* d_ws, size_t ws_size,
                              hipStream_t stream) {
    const float* Qp = (const float*)d_in[0];
    const float* Kp = (const float*)d_in[1];
    const float* Vp = (const float*)d_in[2];
    const int*   VL = (const int*)d_in[3];
    float* Op = (float*)d_out;

    dim3 block(256);
    dim3 grid(NB * (NQ / 32));   // 512 blocks = 2/CU, fully resident
    hipLaunchKernelGGL(attn_fused, grid, block, 0, stream, Qp, Kp, Vp, VL, Op);
}